// Round 1
// baseline (1412.183 us; speedup 1.0000x reference)
//
#include <hip/hip_runtime.h>
#include <math.h>

#define N_NODES 50000
#define N_EDGES 800000
#define E_TOT   850000     // edges + self-loops
#define HEADS   8
#define HID     32
#define C1      256        // HEADS*HID
#define OUTC    16
#define NEG     0.2f
#define EPB     8          // edges per block in k_acc1

__device__ __forceinline__ int f2ord(float f) {
    int b = __float_as_int(f);
    return b >= 0 ? b : (b ^ 0x7fffffff);
}
__device__ __forceinline__ float ord2f(int b) {
    return __int_as_float(b >= 0 ? b : (b ^ 0x7fffffff));
}
__device__ __forceinline__ float lrelu(float v) { return v > 0.0f ? v : NEG * v; }

__global__ void fill_int(int* __restrict__ p, int n, int v) {
    int i = blockIdx.x * blockDim.x + threadIdx.x;
    if (i < n) p[i] = v;
}

// h1[n, h*32+c] = sum_k x[n,k]*W1[k, h*32+c]; a_s/a_d attention dots per (n,h)
__global__ __launch_bounds__(256) void k_h1(
    const float* __restrict__ x, const float* __restrict__ W1,
    const float* __restrict__ att_s, const float* __restrict__ att_d,
    float* __restrict__ h1, float* __restrict__ a_s, float* __restrict__ a_d)
{
    __shared__ float sW[3 * C1];
    __shared__ float sAs[C1], sAd[C1];
    int t = threadIdx.x;
    for (int i = t; i < 3 * C1; i += 256) sW[i] = W1[i];
    for (int i = t; i < C1; i += 256) { sAs[i] = att_s[i]; sAd[i] = att_d[i]; }
    __syncthreads();
    int gid = blockIdx.x * 256 + t;      // node*8 + head
    if (gid >= N_NODES * HEADS) return;
    int n = gid >> 3, h = gid & 7;
    float x0 = x[n * 3], x1 = x[n * 3 + 1], x2 = x[n * 3 + 2];
    float as = 0.0f, ad = 0.0f;
    int base = h * HID;
    float* hrow = h1 + (long)n * C1 + base;
    for (int c = 0; c < HID; c++) {
        float hv = fmaf(x0, sW[base + c], fmaf(x1, sW[C1 + base + c], x2 * sW[2 * C1 + base + c]));
        hrow[c] = hv;
        as = fmaf(hv, sAs[base + c], as);
        ad = fmaf(hv, sAd[base + c], ad);
    }
    a_s[gid] = as; a_d[gid] = ad;
}

__global__ void k_max1(const int* __restrict__ ei,
                       const float* __restrict__ a_s, const float* __restrict__ a_d,
                       int* __restrict__ m1)
{
    int e = blockIdx.x * blockDim.x + threadIdx.x;
    if (e >= E_TOT) return;
    int s, d;
    if (e < N_EDGES) { s = ei[e]; d = ei[N_EDGES + e]; } else { s = d = e - N_EDGES; }
    for (int h = 0; h < HEADS; h++) {
        float v = lrelu(a_s[s * 8 + h] + a_d[d * 8 + h]);
        atomicMax(&m1[d * 8 + h], f2ord(v));
    }
}

// p = exp(e - m); agg[dst,:] += p*h1[src,:]; denom[dst,h] += p
__global__ __launch_bounds__(256) void k_acc1(
    const int* __restrict__ ei, const float* __restrict__ a_s, const float* __restrict__ a_d,
    const int* __restrict__ m1, const float* __restrict__ h1,
    float* __restrict__ agg, float* __restrict__ denom)
{
    int t = threadIdx.x;          // channel 0..255
    int h = t >> 5;               // head
    long e0 = (long)blockIdx.x * EPB;
    for (int k = 0; k < EPB; k++) {
        long e = e0 + k;
        if (e >= E_TOT) break;
        int s, d;
        if (e < N_EDGES) { s = ei[e]; d = ei[N_EDGES + e]; } else { s = d = (int)(e - N_EDGES); }
        float v = lrelu(a_s[s * 8 + h] + a_d[d * 8 + h]);
        float p = __expf(v - ord2f(m1[d * 8 + h]));
        atomicAdd(&agg[(long)d * C1 + t], h1[(long)s * C1 + t] * p);
        if ((t & 31) == 0) atomicAdd(&denom[d * 8 + h], p);
    }
}

// divide by denom, add bias, ELU (in place)
__global__ void k_fin1(float* __restrict__ agg, const float* __restrict__ denom,
                       const float* __restrict__ bias)
{
    long i = (long)blockIdx.x * blockDim.x + threadIdx.x;
    if (i >= (long)N_NODES * C1) return;
    int n = (int)(i >> 8), c = (int)(i & 255), h = c >> 5;
    float v = agg[i] / (denom[n * 8 + h] + 1e-16f) + bias[c];
    agg[i] = v > 0.0f ? v : expm1f(v);
}

// h2 = elu_out @ W2 (256->16), plus attention dots (1 head)
__global__ __launch_bounds__(256) void k_h2(
    const float* __restrict__ elu, const float* __restrict__ W2,
    const float* __restrict__ att_s, const float* __restrict__ att_d,
    float* __restrict__ h2, float* __restrict__ a_s, float* __restrict__ a_d)
{
    __shared__ float sW[C1 * OUTC];   // 16 KB
    int t = threadIdx.x;
    for (int i = t; i < C1 * OUTC; i += 256) sW[i] = W2[i];
    __syncthreads();
    int gid = blockIdx.x * 256 + t;
    int n = gid >> 4, c = gid & 15;
    if (n >= N_NODES) return;
    const float* row = elu + (long)n * C1;
    float acc = 0.0f;
    for (int k = 0; k < C1; k++) acc = fmaf(row[k], sW[k * OUTC + c], acc);
    h2[gid] = acc;
    float rs = acc * att_s[c], rd = acc * att_d[c];
    for (int off = 1; off < 16; off <<= 1) {
        rs += __shfl_xor(rs, off, 64);
        rd += __shfl_xor(rd, off, 64);
    }
    if (c == 0) { a_s[n] = rs; a_d[n] = rd; }
}

__global__ void k_max2(const int* __restrict__ ei,
                       const float* __restrict__ a_s, const float* __restrict__ a_d,
                       int* __restrict__ m2)
{
    int e = blockIdx.x * blockDim.x + threadIdx.x;
    if (e >= E_TOT) return;
    int s, d;
    if (e < N_EDGES) { s = ei[e]; d = ei[N_EDGES + e]; } else { s = d = e - N_EDGES; }
    float v = lrelu(a_s[s] + a_d[d]);
    atomicMax(&m2[d], f2ord(v));
}

__global__ void k_acc2(const int* __restrict__ ei,
                       const float* __restrict__ a_s, const float* __restrict__ a_d,
                       const int* __restrict__ m2, const float* __restrict__ h2,
                       float* __restrict__ out, float* __restrict__ denom)
{
    long gid = (long)blockIdx.x * blockDim.x + threadIdx.x;
    if (gid >= (long)E_TOT * OUTC) return;
    long e = gid >> 4; int c = (int)(gid & 15);
    int s, d;
    if (e < N_EDGES) { s = ei[e]; d = ei[N_EDGES + e]; } else { s = d = (int)(e - N_EDGES); }
    float v = lrelu(a_s[s] + a_d[d]);
    float p = __expf(v - ord2f(m2[d]));
    atomicAdd(&out[d * OUTC + c], h2[s * OUTC + c] * p);
    if (c == 0) atomicAdd(&denom[d], p);
}

__global__ void k_fin2(float* __restrict__ out, const float* __restrict__ denom,
                       const float* __restrict__ bias)
{
    int i = blockIdx.x * blockDim.x + threadIdx.x;
    if (i >= N_NODES * OUTC) return;
    int n = i >> 4, c = i & 15;
    out[i] = out[i] / (denom[n] + 1e-16f) + bias[c];
}

extern "C" void kernel_launch(void* const* d_in, const int* in_sizes, int n_in,
                              void* d_out, int out_size, void* d_ws, size_t ws_size,
                              hipStream_t stream)
{
    (void)in_sizes; (void)n_in; (void)out_size; (void)ws_size;
    const float* x    = (const float*)d_in[0];
    const int*   ei   = (const int*)d_in[1];
    const float* W1   = (const float*)d_in[2];
    const float* as1w = (const float*)d_in[3];
    const float* ad1w = (const float*)d_in[4];
    const float* b1   = (const float*)d_in[5];
    const float* W2   = (const float*)d_in[6];
    const float* as2w = (const float*)d_in[7];
    const float* ad2w = (const float*)d_in[8];
    const float* b2   = (const float*)d_in[9];
    float* out = (float*)d_out;

    const long N = N_NODES;
    float* ws   = (float*)d_ws;
    float* h1v  = ws;                    // N*256
    float* agg1 = ws + N * C1;           // N*256 (becomes ELU output in place)
    float* a_s1 = ws + 2 * N * C1;       // N*8
    float* a_d1 = a_s1 + N * HEADS;      // N*8
    int*   m1   = (int*)(a_d1 + N * HEADS);      // N*8
    float* den1 = (float*)(m1 + N * HEADS);      // N*8
    float* h2v  = den1 + N * HEADS;      // N*16
    float* a_s2 = h2v + N * OUTC;        // N
    float* a_d2 = a_s2 + N;              // N
    int*   m2   = (int*)(a_d2 + N);      // N
    float* den2 = (float*)(m2 + N);      // N

    hipMemsetAsync(agg1, 0, (size_t)N * C1 * sizeof(float), stream);
    hipMemsetAsync(den1, 0, (size_t)N * HEADS * sizeof(float), stream);
    hipMemsetAsync(den2, 0, (size_t)N * sizeof(float), stream);
    hipMemsetAsync(out,  0, (size_t)N * OUTC * sizeof(float), stream);
    fill_int<<<(N * HEADS + 255) / 256, 256, 0, stream>>>(m1, N * HEADS, (int)0x80000000);
    fill_int<<<(N + 255) / 256, 256, 0, stream>>>(m2, (int)N, (int)0x80000000);

    k_h1<<<(N * HEADS + 255) / 256, 256, 0, stream>>>(x, W1, as1w, ad1w, h1v, a_s1, a_d1);
    k_max1<<<(E_TOT + 255) / 256, 256, 0, stream>>>(ei, a_s1, a_d1, m1);
    k_acc1<<<(E_TOT + EPB - 1) / EPB, 256, 0, stream>>>(ei, a_s1, a_d1, m1, h1v, agg1, den1);
    k_fin1<<<(N * C1 + 255) / 256, 256, 0, stream>>>(agg1, den1, b1);

    k_h2<<<(N * OUTC + 255) / 256, 256, 0, stream>>>(agg1, W2, as2w, ad2w, h2v, a_s2, a_d2);
    k_max2<<<(E_TOT + 255) / 256, 256, 0, stream>>>(ei, a_s2, a_d2, m2);
    k_acc2<<<((long)E_TOT * OUTC + 255) / 256, 256, 0, stream>>>(ei, a_s2, a_d2, m2, h2v, out, den2);
    k_fin2<<<(N * OUTC + 255) / 256, 256, 0, stream>>>(out, den2, b2);
}

// Round 2
// 285.134 us; speedup vs baseline: 4.9527x; 4.9527x over previous
//
#include <hip/hip_runtime.h>
#include <math.h>

#define N_NODES 50000
#define N_EDGES 800000
#define E_TOT   850000     // edges + self-loops
#define HEADS   8
#define HID     32
#define C1      256        // HEADS*HID
#define OUTC    16
#define NEG     0.2f
#define NB1     ((N_NODES + 255) / 256)   // scan level-1 blocks = 196

__device__ __forceinline__ float lrelu(float v) { return v > 0.0f ? v : NEG * v; }

// ---- tiny precompute: As1[k][h] = sum_c W1[k][h*32+c] * att_s1[h][c] ----
__global__ void k_prep_att(const float* __restrict__ W1,
                           const float* __restrict__ att_s, const float* __restrict__ att_d,
                           float* __restrict__ As1, float* __restrict__ Ad1)
{
    int id = threadIdx.x;            // 0..23
    if (id >= 24) return;
    int k = id / 8, h = id % 8;
    float as = 0.0f, ad = 0.0f;
    for (int c = 0; c < HID; c++) {
        float w = W1[k * C1 + h * HID + c];
        as = fmaf(w, att_s[h * HID + c], as);
        ad = fmaf(w, att_d[h * HID + c], ad);
    }
    As1[k * 8 + h] = as; Ad1[k * 8 + h] = ad;
}

// ---- a_s1[n*8+h] = x[n,:] @ As1[:,h]  (rank-3, no h1 needed) ----
__global__ __launch_bounds__(256) void k_as1(
    const float* __restrict__ x, const float* __restrict__ As1, const float* __restrict__ Ad1,
    float* __restrict__ a_s, float* __restrict__ a_d)
{
    int gid = blockIdx.x * 256 + threadIdx.x;
    if (gid >= N_NODES * HEADS) return;
    int n = gid >> 3, h = gid & 7;
    float x0 = x[n * 3], x1 = x[n * 3 + 1], x2 = x[n * 3 + 2];
    a_s[gid] = fmaf(x0, As1[h], fmaf(x1, As1[8 + h], x2 * As1[16 + h]));
    a_d[gid] = fmaf(x0, Ad1[h], fmaf(x1, Ad1[8 + h], x2 * Ad1[16 + h]));
}

// ---- CSR build ----
__global__ void k_count(const int* __restrict__ ei, int* __restrict__ cnt)
{
    int e = blockIdx.x * blockDim.x + threadIdx.x;
    if (e >= E_TOT) return;
    int d = (e < N_EDGES) ? ei[N_EDGES + e] : (e - N_EDGES);
    atomicAdd(&cnt[d], 1);
}

__global__ void k_scan1(const int* __restrict__ cnt, int* __restrict__ part,
                        int* __restrict__ bsum)
{
    __shared__ int s[256];
    int tid = threadIdx.x;
    int i = blockIdx.x * 256 + tid;
    int v = (i < N_NODES) ? cnt[i] : 0;
    s[tid] = v;
    __syncthreads();
    for (int o = 1; o < 256; o <<= 1) {
        int t = (tid >= o) ? s[tid - o] : 0;
        __syncthreads();
        s[tid] += t;
        __syncthreads();
    }
    if (i < N_NODES) part[i] = s[tid] - v;   // exclusive
    if (tid == 255) bsum[blockIdx.x] = s[255];
}

__global__ void k_scan2(int* __restrict__ bsum)
{
    __shared__ int s[256];
    int tid = threadIdx.x;
    int v = (tid < NB1) ? bsum[tid] : 0;
    s[tid] = v;
    __syncthreads();
    for (int o = 1; o < 256; o <<= 1) {
        int t = (tid >= o) ? s[tid - o] : 0;
        __syncthreads();
        s[tid] += t;
        __syncthreads();
    }
    if (tid < NB1) bsum[tid] = s[tid] - v;   // exclusive
}

__global__ void k_scan3(const int* __restrict__ part, const int* __restrict__ bsum,
                        int* __restrict__ off, int* __restrict__ woff)
{
    int i = blockIdx.x * 256 + threadIdx.x;
    if (i < N_NODES) {
        int o = part[i] + bsum[blockIdx.x];
        off[i] = o; woff[i] = o;
    }
    if (i == 0) off[N_NODES] = E_TOT;
}

__global__ void k_fill(const int* __restrict__ ei, int* __restrict__ woff,
                       int* __restrict__ csr_src)
{
    int e = blockIdx.x * blockDim.x + threadIdx.x;
    if (e >= E_TOT) return;
    int s, d;
    if (e < N_EDGES) { s = ei[e]; d = ei[N_EDGES + e]; } else { s = d = e - N_EDGES; }
    int pos = atomicAdd(&woff[d], 1);
    csr_src[pos] = s;
}

// ---- layer-1 aggregation: 8 lanes per dst (lane = head), no atomics ----
// accumulate xacc[dst][h][0..2] = sum_e p * x[src], den1[dst][h] = sum_e p
__global__ __launch_bounds__(256) void k_agg1(
    const int* __restrict__ off, const int* __restrict__ csr_src,
    const float* __restrict__ a_s, const float* __restrict__ a_d,
    const float* __restrict__ x,
    float* __restrict__ xacc, float* __restrict__ den1)
{
    int tid = threadIdx.x;
    int h = tid & 7;
    int dst = blockIdx.x * 32 + (tid >> 3);
    if (dst >= N_NODES) return;
    int beg = off[dst], end = off[dst + 1];
    float ad = a_d[dst * 8 + h];
    // pass 1: max
    float m = -1e30f;
    for (int i = beg; i < end; i++) {
        float e = lrelu(a_s[csr_src[i] * 8 + h] + ad);
        m = fmaxf(m, e);
    }
    // pass 2: exp-accumulate
    float den = 0.0f, xa0 = 0.0f, xa1 = 0.0f, xa2 = 0.0f;
    for (int i = beg; i < end; i++) {
        int s = csr_src[i];
        float e = lrelu(a_s[s * 8 + h] + ad);
        float p = __expf(e - m);
        den += p;
        xa0 = fmaf(p, x[s * 3],     xa0);
        xa1 = fmaf(p, x[s * 3 + 1], xa1);
        xa2 = fmaf(p, x[s * 3 + 2], xa2);
    }
    int b = (dst * 8 + h) * 3;
    xacc[b] = xa0; xacc[b + 1] = xa1; xacc[b + 2] = xa2;
    den1[dst * 8 + h] = den;
}

// ---- finalize layer 1: elu1[n, h*32+c] = ELU( xacc[n,h,:]@W1[:,h*32+c]/den + bias ) ----
__global__ __launch_bounds__(256) void k_fin1(
    const float* __restrict__ xacc, const float* __restrict__ den1,
    const float* __restrict__ W1, const float* __restrict__ bias,
    float* __restrict__ elu1)
{
    long gid = (long)blockIdx.x * 256 + threadIdx.x;
    if (gid >= (long)N_NODES * C1) return;
    int n = (int)(gid >> 8), c = (int)(gid & 255), h = c >> 5;
    int b = (n * 8 + h) * 3;
    float v = xacc[b] * W1[c] + xacc[b + 1] * W1[C1 + c] + xacc[b + 2] * W1[2 * C1 + c];
    v = v / (den1[n * 8 + h] + 1e-16f) + bias[c];
    elu1[gid] = v > 0.0f ? v : expm1f(v);
}

// ---- h2 = elu1 @ W2 (256->16) + attention dots (1 head) ----
__global__ __launch_bounds__(256) void k_h2(
    const float* __restrict__ elu, const float* __restrict__ W2,
    const float* __restrict__ att_s, const float* __restrict__ att_d,
    float* __restrict__ h2, float* __restrict__ a_s, float* __restrict__ a_d)
{
    __shared__ float sW[C1 * OUTC];   // 16 KB
    int t = threadIdx.x;
    for (int i = t; i < C1 * OUTC; i += 256) sW[i] = W2[i];
    __syncthreads();
    int gid = blockIdx.x * 256 + t;
    int n = gid >> 4, c = gid & 15;
    if (n >= N_NODES) return;
    const float* row = elu + (long)n * C1;
    float acc = 0.0f;
    for (int k = 0; k < C1; k++) acc = fmaf(row[k], sW[k * OUTC + c], acc);
    h2[gid] = acc;
    float rs = acc * att_s[c], rd = acc * att_d[c];
    for (int o = 1; o < 16; o <<= 1) {
        rs += __shfl_xor(rs, o, 64);
        rd += __shfl_xor(rd, o, 64);
    }
    if (c == 0) { a_s[n] = rs; a_d[n] = rd; }
}

// ---- layer-2 aggregation: 16 lanes per dst (lane = channel), no atomics ----
__global__ __launch_bounds__(256) void k_agg2(
    const int* __restrict__ off, const int* __restrict__ csr_src,
    const float* __restrict__ a_s, const float* __restrict__ a_d,
    const float* __restrict__ h2, const float* __restrict__ bias,
    float* __restrict__ out)
{
    int tid = threadIdx.x;
    int c = tid & 15;
    int dst = blockIdx.x * 16 + (tid >> 4);
    if (dst >= N_NODES) return;
    int beg = off[dst], end = off[dst + 1];
    float ad = a_d[dst];
    // pass 1: strided max across 16 lanes
    float m = -1e30f;
    for (int i = beg + c; i < end; i += 16) {
        float e = lrelu(a_s[csr_src[i]] + ad);
        m = fmaxf(m, e);
    }
    for (int o = 1; o < 16; o <<= 1) m = fmaxf(m, __shfl_xor(m, o, 64));
    // pass 2: all 16 lanes walk edges together; lane owns channel c
    float acc = 0.0f, den = 0.0f;
    for (int i = beg; i < end; i++) {
        int s = csr_src[i];
        float p = __expf(lrelu(a_s[s] + ad) - m);
        den += p;
        acc = fmaf(p, h2[s * OUTC + c], acc);
    }
    out[dst * OUTC + c] = acc / (den + 1e-16f) + bias[c];
}

extern "C" void kernel_launch(void* const* d_in, const int* in_sizes, int n_in,
                              void* d_out, int out_size, void* d_ws, size_t ws_size,
                              hipStream_t stream)
{
    (void)in_sizes; (void)n_in; (void)out_size; (void)ws_size;
    const float* x    = (const float*)d_in[0];
    const int*   ei   = (const int*)d_in[1];
    const float* W1   = (const float*)d_in[2];
    const float* as1w = (const float*)d_in[3];
    const float* ad1w = (const float*)d_in[4];
    const float* b1   = (const float*)d_in[5];
    const float* W2   = (const float*)d_in[6];
    const float* as2w = (const float*)d_in[7];
    const float* ad2w = (const float*)d_in[8];
    const float* b2   = (const float*)d_in[9];
    float* out = (float*)d_out;

    const long N = N_NODES;
    char* p = (char*)d_ws;
    auto alloc = [&](size_t elems) { void* r = p; p += elems * 4; return r; };

    int*   cnt     = (int*)alloc(N);
    int*   part    = (int*)alloc(N);
    int*   off     = (int*)alloc(N + 1);
    int*   woff    = (int*)alloc(N);
    int*   bsum    = (int*)alloc(256);
    int*   csr_src = (int*)alloc(E_TOT);
    float* As1     = (float*)alloc(32);
    float* Ad1     = (float*)alloc(32);
    float* a_s1    = (float*)alloc(N * HEADS);
    float* a_d1    = (float*)alloc(N * HEADS);
    float* xacc    = (float*)alloc(N * HEADS * 3);
    float* den1    = (float*)alloc(N * HEADS);
    float* elu1    = (float*)alloc(N * C1);
    float* h2v     = (float*)alloc(N * OUTC);
    float* a_s2    = (float*)alloc(N);
    float* a_d2    = (float*)alloc(N);

    hipMemsetAsync(cnt, 0, (size_t)N * sizeof(int), stream);

    k_prep_att<<<1, 64, 0, stream>>>(W1, as1w, ad1w, As1, Ad1);
    k_as1<<<(N * HEADS + 255) / 256, 256, 0, stream>>>(x, As1, Ad1, a_s1, a_d1);
    k_count<<<(E_TOT + 255) / 256, 256, 0, stream>>>(ei, cnt);
    k_scan1<<<NB1, 256, 0, stream>>>(cnt, part, bsum);
    k_scan2<<<1, 256, 0, stream>>>(bsum);
    k_scan3<<<NB1, 256, 0, stream>>>(part, bsum, off, woff);
    k_fill<<<(E_TOT + 255) / 256, 256, 0, stream>>>(ei, woff, csr_src);

    k_agg1<<<(N + 31) / 32, 256, 0, stream>>>(off, csr_src, a_s1, a_d1, x, xacc, den1);
    k_fin1<<<(int)((N * C1 + 255) / 256), 256, 0, stream>>>(xacc, den1, W1, b1, elu1);

    k_h2<<<(N * OUTC + 255) / 256, 256, 0, stream>>>(elu1, W2, as2w, ad2w, h2v, a_s2, a_d2);
    k_agg2<<<(N + 15) / 16, 256, 0, stream>>>(off, csr_src, a_s2, a_d2, h2v, b2, out);
}

// Round 3
// 216.471 us; speedup vs baseline: 6.5236x; 1.3172x over previous
//
#include <hip/hip_runtime.h>
#include <math.h>

#define N_NODES 50000
#define N_EDGES 800000
#define E_TOT   850000     // edges + self-loops
#define HEADS   8
#define HID     32
#define C1      256        // HEADS*HID
#define OUTC    16
#define NEG     0.2f
#define NB1     ((N_NODES + 255) / 256)   // scan level-1 blocks = 196

__device__ __forceinline__ float lrelu(float v) { return v > 0.0f ? v : NEG * v; }

// ---- precompute: As1[k][h]=sum_c W1[k,h*32+c]*att_s1[h,c];  As2[k]=sum_j W2[k,j]*att_s2[j]
__global__ void k_prep(const float* __restrict__ W1,
                       const float* __restrict__ att_s1, const float* __restrict__ att_d1,
                       const float* __restrict__ W2,
                       const float* __restrict__ att_s2, const float* __restrict__ att_d2,
                       float* __restrict__ As1, float* __restrict__ Ad1,
                       float* __restrict__ As2, float* __restrict__ Ad2)
{
    int t = threadIdx.x;
    if (t < 24) {
        int k = t / 8, h = t % 8;
        float as = 0.0f, ad = 0.0f;
        for (int c = 0; c < HID; c++) {
            float w = W1[k * C1 + h * HID + c];
            as = fmaf(w, att_s1[h * HID + c], as);
            ad = fmaf(w, att_d1[h * HID + c], ad);
        }
        As1[k * 8 + h] = as; Ad1[k * 8 + h] = ad;
    }
    // t = k in [0,256)
    float as2 = 0.0f, ad2 = 0.0f;
    for (int j = 0; j < OUTC; j++) {
        float w = W2[t * OUTC + j];
        as2 = fmaf(w, att_s2[j], as2);
        ad2 = fmaf(w, att_d2[j], ad2);
    }
    As2[t] = as2; Ad2[t] = ad2;
}

// ---- a_s1[n*8+h] = x[n,:]@As1[:,h]; also pack xp[n] = (x0,x1,x2,1) ----
__global__ __launch_bounds__(256) void k_as1(
    const float* __restrict__ x, const float* __restrict__ As1, const float* __restrict__ Ad1,
    float* __restrict__ a_s, float* __restrict__ a_d, float4* __restrict__ xp)
{
    int gid = blockIdx.x * 256 + threadIdx.x;
    if (gid >= N_NODES * HEADS) return;
    int n = gid >> 3, h = gid & 7;
    float x0 = x[n * 3], x1 = x[n * 3 + 1], x2 = x[n * 3 + 2];
    a_s[gid] = fmaf(x0, As1[h], fmaf(x1, As1[8 + h], x2 * As1[16 + h]));
    a_d[gid] = fmaf(x0, Ad1[h], fmaf(x1, Ad1[8 + h], x2 * Ad1[16 + h]));
    if (h == 0) xp[n] = make_float4(x0, x1, x2, 1.0f);
}

// ---- CSR build: count + rank in one pass ----
__global__ void k_count(const int* __restrict__ ei, int* __restrict__ cnt,
                        int* __restrict__ rank)
{
    int e = blockIdx.x * blockDim.x + threadIdx.x;
    if (e >= E_TOT) return;
    int d = (e < N_EDGES) ? ei[N_EDGES + e] : (e - N_EDGES);
    rank[e] = atomicAdd(&cnt[d], 1);
}

__global__ void k_scan1(const int* __restrict__ cnt, int* __restrict__ part,
                        int* __restrict__ bsum)
{
    __shared__ int s[256];
    int tid = threadIdx.x;
    int i = blockIdx.x * 256 + tid;
    int v = (i < N_NODES) ? cnt[i] : 0;
    s[tid] = v;
    __syncthreads();
    for (int o = 1; o < 256; o <<= 1) {
        int t = (tid >= o) ? s[tid - o] : 0;
        __syncthreads();
        s[tid] += t;
        __syncthreads();
    }
    if (i < N_NODES) part[i] = s[tid] - v;   // exclusive
    if (tid == 255) bsum[blockIdx.x] = s[255];
}

__global__ void k_scan2(int* __restrict__ bsum)
{
    __shared__ int s[256];
    int tid = threadIdx.x;
    int v = (tid < NB1) ? bsum[tid] : 0;
    s[tid] = v;
    __syncthreads();
    for (int o = 1; o < 256; o <<= 1) {
        int t = (tid >= o) ? s[tid - o] : 0;
        __syncthreads();
        s[tid] += t;
        __syncthreads();
    }
    if (tid < NB1) bsum[tid] = s[tid] - v;   // exclusive
}

__global__ void k_scan3(const int* __restrict__ part, const int* __restrict__ bsum,
                        int* __restrict__ off)
{
    int i = blockIdx.x * 256 + threadIdx.x;
    if (i < N_NODES) off[i] = part[i] + bsum[blockIdx.x];
    if (i == 0) off[N_NODES] = E_TOT;
}

// ---- fill: no atomics (rank precomputed) ----
__global__ void k_fill(const int* __restrict__ ei, const int* __restrict__ rank,
                       const int* __restrict__ off, int* __restrict__ csr_src)
{
    int e = blockIdx.x * blockDim.x + threadIdx.x;
    if (e >= E_TOT) return;
    int s, d;
    if (e < N_EDGES) { s = ei[e]; d = ei[N_EDGES + e]; } else { s = d = e - N_EDGES; }
    csr_src[off[d] + rank[e]] = s;
}

// ---- layer-1 aggregation: single pass (no max), float4 payload incl. denom ----
__global__ __launch_bounds__(256) void k_agg1(
    const int* __restrict__ off, const int* __restrict__ csr_src,
    const float* __restrict__ a_s, const float* __restrict__ a_d,
    const float4* __restrict__ xp, float4* __restrict__ xaccw)
{
    int tid = threadIdx.x;
    int h = tid & 7;
    int dst = blockIdx.x * 32 + (tid >> 3);
    if (dst >= N_NODES) return;
    int beg = off[dst], end = off[dst + 1];
    float ad = a_d[dst * 8 + h];
    float a0 = 0.0f, a1 = 0.0f, a2 = 0.0f, a3 = 0.0f;
    for (int i = beg; i < end; i++) {
        int s = csr_src[i];
        float p = __expf(lrelu(a_s[s * 8 + h] + ad));
        float4 xv = xp[s];
        a0 = fmaf(p, xv.x, a0);
        a1 = fmaf(p, xv.y, a1);
        a2 = fmaf(p, xv.z, a2);
        a3 += p;                       // denom
    }
    xaccw[dst * 8 + h] = make_float4(a0, a1, a2, a3);
}

// ---- fused finalize layer1 + layer2 transform (elu1 never hits global) ----
// block = 256 threads = 16 nodes x 16 lanes
__global__ __launch_bounds__(256) void k_fin1h2(
    const float4* __restrict__ xaccw, const float* __restrict__ W1,
    const float* __restrict__ b1, const float* __restrict__ W2,
    const float* __restrict__ As2, const float* __restrict__ Ad2,
    float* __restrict__ h2, float* __restrict__ a_s2, float* __restrict__ a_d2)
{
    __shared__ float sW1[3 * C1];        // 3 KB
    __shared__ float sAux[3 * C1];       // b1 | As2 | Ad2, 3 KB
    __shared__ float sW2t[OUTC][260];    // transposed, padded: 16.6 KB
    __shared__ float sElu[16][260];      // padded: 16.6 KB
    int t = threadIdx.x;
    for (int i = t; i < 3 * C1; i += 256) sW1[i] = W1[i];
    sAux[t] = b1[t]; sAux[C1 + t] = As2[t]; sAux[2 * C1 + t] = Ad2[t];
    for (int i = t; i < C1 * OUTC; i += 256) {
        int k = i >> 4, j = i & 15;
        sW2t[j][k] = W2[i];
    }
    __syncthreads();
    int n = t >> 4, l = t & 15;
    int node = blockIdx.x * 16 + n;
    float as = 0.0f, ad = 0.0f;
    for (int i = 0; i < 16; i++) {
        int c = l + 16 * i;
        int h = c >> 5;
        float4 xa = xaccw[node * 8 + h];
        float z = (xa.x * sW1[c] + xa.y * sW1[C1 + c] + xa.z * sW1[2 * C1 + c])
                  / (xa.w + 1e-16f) + sAux[c];
        float e = z > 0.0f ? z : expm1f(z);
        sElu[n][c] = e;
        as = fmaf(e, sAux[C1 + c], as);
        ad = fmaf(e, sAux[2 * C1 + c], ad);
    }
    for (int o = 1; o < 16; o <<= 1) {
        as += __shfl_xor(as, o, 64);
        ad += __shfl_xor(ad, o, 64);
    }
    if (l == 0) { a_s2[node] = as; a_d2[node] = ad; }
    __syncthreads();
    // phase 2: h2[node, l] = elu_row . W2[:, l]
    const float4* e4 = (const float4*)&sElu[n][0];
    const float4* w4 = (const float4*)&sW2t[l][0];
    float acc = 0.0f;
    #pragma unroll 8
    for (int k = 0; k < 64; k++) {
        float4 a = e4[k], b = w4[k];
        acc = fmaf(a.x, b.x, fmaf(a.y, b.y, fmaf(a.z, b.z, fmaf(a.w, b.w, acc))));
    }
    h2[node * OUTC + l] = acc;
}

// ---- layer-2 aggregation: single pass (no max), 16 lanes per dst ----
__global__ __launch_bounds__(256) void k_agg2(
    const int* __restrict__ off, const int* __restrict__ csr_src,
    const float* __restrict__ a_s, const float* __restrict__ a_d,
    const float* __restrict__ h2, const float* __restrict__ bias,
    float* __restrict__ out)
{
    int tid = threadIdx.x;
    int c = tid & 15;
    int dst = blockIdx.x * 16 + (tid >> 4);
    if (dst >= N_NODES) return;
    int beg = off[dst], end = off[dst + 1];
    float ad = a_d[dst];
    float acc = 0.0f, den = 0.0f;
    for (int i = beg; i < end; i++) {
        int s = csr_src[i];
        float p = __expf(lrelu(a_s[s] + ad));
        den += p;
        acc = fmaf(p, h2[s * OUTC + c], acc);
    }
    out[dst * OUTC + c] = acc / (den + 1e-16f) + bias[c];
}

extern "C" void kernel_launch(void* const* d_in, const int* in_sizes, int n_in,
                              void* d_out, int out_size, void* d_ws, size_t ws_size,
                              hipStream_t stream)
{
    (void)in_sizes; (void)n_in; (void)out_size; (void)ws_size;
    const float* x    = (const float*)d_in[0];
    const int*   ei   = (const int*)d_in[1];
    const float* W1   = (const float*)d_in[2];
    const float* as1w = (const float*)d_in[3];
    const float* ad1w = (const float*)d_in[4];
    const float* b1   = (const float*)d_in[5];
    const float* W2   = (const float*)d_in[6];
    const float* as2w = (const float*)d_in[7];
    const float* ad2w = (const float*)d_in[8];
    const float* b2   = (const float*)d_in[9];
    float* out = (float*)d_out;

    const long N = N_NODES;
    char* p = (char*)d_ws;
    auto alloc = [&](size_t elems) {          // 16B-aligned allocations
        void* r = p; p += ((elems + 3) & ~(size_t)3) * 4; return r;
    };

    float4* xp      = (float4*)alloc(N * 4);
    float4* xaccw   = (float4*)alloc(N * HEADS * 4);
    int*   cnt      = (int*)alloc(N);
    int*   part     = (int*)alloc(N);
    int*   off      = (int*)alloc(N + 1);
    int*   bsum     = (int*)alloc(256);
    int*   rank     = (int*)alloc(E_TOT);
    int*   csr_src  = (int*)alloc(E_TOT);
    float* As1      = (float*)alloc(32);
    float* Ad1      = (float*)alloc(32);
    float* As2      = (float*)alloc(C1);
    float* Ad2      = (float*)alloc(C1);
    float* a_s1     = (float*)alloc(N * HEADS);
    float* a_d1     = (float*)alloc(N * HEADS);
    float* h2v      = (float*)alloc(N * OUTC);
    float* a_s2     = (float*)alloc(N);
    float* a_d2     = (float*)alloc(N);

    hipMemsetAsync(cnt, 0, (size_t)N * sizeof(int), stream);

    k_prep<<<1, 256, 0, stream>>>(W1, as1w, ad1w, W2, as2w, ad2w, As1, Ad1, As2, Ad2);
    k_as1<<<(N * HEADS + 255) / 256, 256, 0, stream>>>(x, As1, Ad1, a_s1, a_d1, xp);
    k_count<<<(E_TOT + 255) / 256, 256, 0, stream>>>(ei, cnt, rank);
    k_scan1<<<NB1, 256, 0, stream>>>(cnt, part, bsum);
    k_scan2<<<1, 256, 0, stream>>>(bsum);
    k_scan3<<<NB1, 256, 0, stream>>>(part, bsum, off);
    k_fill<<<(E_TOT + 255) / 256, 256, 0, stream>>>(ei, rank, off, csr_src);

    k_agg1<<<(int)((N + 31) / 32), 256, 0, stream>>>(off, csr_src, a_s1, a_d1, xp, xaccw);
    k_fin1h2<<<(int)(N / 16), 256, 0, stream>>>(xaccw, W1, b1, W2, As2, Ad2, h2v, a_s2, a_d2);
    k_agg2<<<(int)(N / 16), 256, 0, stream>>>(off, csr_src, a_s2, a_d2, h2v, b2, out);
}

// Round 4
// 196.565 us; speedup vs baseline: 7.1843x; 1.1013x over previous
//
#include <hip/hip_runtime.h>
#include <math.h>

#define N_NODES 50000
#define N_EDGES 800000
#define E_TOT   850000     // edges + self-loops
#define HEADS   8
#define HID     32
#define C1      256        // HEADS*HID
#define OUTC    16
#define NEG     0.2f
#define NB1     ((N_NODES + 255) / 256)   // scan level-1 blocks = 196

__device__ __forceinline__ float lrelu(float v) { return v > 0.0f ? v : NEG * v; }

// ---- fused setup: attention-weight folding + xp pack + CSR count/rank ----
// As1[k][h]=sum_c W1[k,h*32+c]*att_s1[h,c];  As2[k]=sum_j W2[k,j]*att_s2[j]
__global__ __launch_bounds__(256) void k_setup(
    const float* __restrict__ x, const int* __restrict__ ei,
    const float* __restrict__ W1,
    const float* __restrict__ att_s1, const float* __restrict__ att_d1,
    const float* __restrict__ W2,
    const float* __restrict__ att_s2, const float* __restrict__ att_d2,
    float4* __restrict__ xp, int* __restrict__ cnt, int* __restrict__ rank,
    float* __restrict__ As1, float* __restrict__ Ad1,
    float* __restrict__ As2, float* __restrict__ Ad2)
{
    int t = threadIdx.x;
    int e = blockIdx.x * 256 + t;
    if (blockIdx.x == 0) {
        if (t < 24) {
            int k = t / 8, h = t % 8;
            float as = 0.0f, ad = 0.0f;
            for (int c = 0; c < HID; c++) {
                float w = W1[k * C1 + h * HID + c];
                as = fmaf(w, att_s1[h * HID + c], as);
                ad = fmaf(w, att_d1[h * HID + c], ad);
            }
            As1[k * 8 + h] = as; Ad1[k * 8 + h] = ad;
        }
        float as2 = 0.0f, ad2 = 0.0f;
        for (int j = 0; j < OUTC; j++) {
            float w = W2[t * OUTC + j];
            as2 = fmaf(w, att_s2[j], as2);
            ad2 = fmaf(w, att_d2[j], ad2);
        }
        As2[t] = as2; Ad2[t] = ad2;
    }
    if (e < N_NODES)
        xp[e] = make_float4(x[e * 3], x[e * 3 + 1], x[e * 3 + 2], 1.0f);
    if (e < E_TOT) {
        int d = (e < N_EDGES) ? ei[N_EDGES + e] : (e - N_EDGES);
        rank[e] = atomicAdd(&cnt[d], 1);
    }
}

__global__ void k_scan1(const int* __restrict__ cnt, int* __restrict__ part,
                        int* __restrict__ bsum)
{
    __shared__ int s[256];
    int tid = threadIdx.x;
    int i = blockIdx.x * 256 + tid;
    int v = (i < N_NODES) ? cnt[i] : 0;
    s[tid] = v;
    __syncthreads();
    for (int o = 1; o < 256; o <<= 1) {
        int t = (tid >= o) ? s[tid - o] : 0;
        __syncthreads();
        s[tid] += t;
        __syncthreads();
    }
    if (i < N_NODES) part[i] = s[tid] - v;   // exclusive
    if (tid == 255) bsum[blockIdx.x] = s[255];
}

__global__ void k_scan2(int* __restrict__ bsum)
{
    __shared__ int s[256];
    int tid = threadIdx.x;
    int v = (tid < NB1) ? bsum[tid] : 0;
    s[tid] = v;
    __syncthreads();
    for (int o = 1; o < 256; o <<= 1) {
        int t = (tid >= o) ? s[tid - o] : 0;
        __syncthreads();
        s[tid] += t;
        __syncthreads();
    }
    if (tid < NB1) bsum[tid] = s[tid] - v;   // exclusive
}

__global__ void k_scan3(const int* __restrict__ part, const int* __restrict__ bsum,
                        int* __restrict__ off)
{
    int i = blockIdx.x * 256 + threadIdx.x;
    if (i < N_NODES) off[i] = part[i] + bsum[blockIdx.x];
    if (i == 0) off[N_NODES] = E_TOT;
}

__global__ void k_fill(const int* __restrict__ ei, const int* __restrict__ rank,
                       const int* __restrict__ off, int* __restrict__ csr_src)
{
    int e = blockIdx.x * blockDim.x + threadIdx.x;
    if (e >= E_TOT) return;
    int s, d;
    if (e < N_EDGES) { s = ei[e]; d = ei[N_EDGES + e]; } else { s = d = e - N_EDGES; }
    csr_src[off[d] + rank[e]] = s;
}

// ---- layer-1 aggregation: 8 lanes per dst (lane = head) ----
// batch of 8 edges: each lane loads one edge's (csr, xp) in parallel,
// then an unrolled shfl loop distributes; a_s recomputed from xp (rank-3).
__global__ __launch_bounds__(256) void k_agg1(
    const int* __restrict__ off, const int* __restrict__ csr_src,
    const float4* __restrict__ xp,
    const float* __restrict__ As1, const float* __restrict__ Ad1,
    float4* __restrict__ xaccw)
{
    int tid = threadIdx.x;
    int h = tid & 7;
    int dst = blockIdx.x * 32 + (tid >> 3);
    if (dst >= N_NODES) return;
    float s0 = As1[h], s1 = As1[8 + h], s2 = As1[16 + h];
    float d0 = Ad1[h], d1 = Ad1[8 + h], d2 = Ad1[16 + h];
    float4 xd = xp[dst];
    float ad = xd.x * d0 + xd.y * d1 + xd.z * d2;
    int beg = off[dst], end = off[dst + 1];
    float a0 = 0.0f, a1 = 0.0f, a2 = 0.0f, a3 = 0.0f;
    int nfull = beg + ((end - beg) & ~7);
    for (int base = beg; base < nfull; base += 8) {
        int sm = csr_src[base + h];
        float4 xv = xp[sm];
        #pragma unroll
        for (int j = 0; j < 8; j++) {
            float vx = __shfl(xv.x, j, 8);
            float vy = __shfl(xv.y, j, 8);
            float vz = __shfl(xv.z, j, 8);
            float as = vx * s0 + vy * s1 + vz * s2;
            float p = __expf(lrelu(as + ad));
            a0 = fmaf(p, vx, a0);
            a1 = fmaf(p, vy, a1);
            a2 = fmaf(p, vz, a2);
            a3 += p;
        }
    }
    if (nfull < end) {                      // tail (< 8 edges)
        int idx = nfull + h;
        int sm = (idx < end) ? csr_src[idx] : 0;
        float4 xv = xp[sm];
        int m = end - nfull;
        for (int j = 0; j < m; j++) {
            float vx = __shfl(xv.x, j, 8);
            float vy = __shfl(xv.y, j, 8);
            float vz = __shfl(xv.z, j, 8);
            float as = vx * s0 + vy * s1 + vz * s2;
            float p = __expf(lrelu(as + ad));
            a0 = fmaf(p, vx, a0);
            a1 = fmaf(p, vy, a1);
            a2 = fmaf(p, vz, a2);
            a3 += p;
        }
    }
    xaccw[dst * 8 + h] = make_float4(a0, a1, a2, a3);
}

// ---- fused finalize layer1 + layer2 transform (elu1 never hits global) ----
// block = 256 threads = 16 nodes x 16 lanes
__global__ __launch_bounds__(256) void k_fin1h2(
    const float4* __restrict__ xaccw, const float* __restrict__ W1,
    const float* __restrict__ b1, const float* __restrict__ W2,
    const float* __restrict__ As2, const float* __restrict__ Ad2,
    float* __restrict__ h2, float* __restrict__ a_s2, float* __restrict__ a_d2)
{
    __shared__ float sW1[3 * C1];        // 3 KB
    __shared__ float sAux[3 * C1];       // b1 | As2 | Ad2, 3 KB
    __shared__ float sW2t[OUTC][260];    // transposed, padded
    __shared__ float sElu[16][260];      // padded
    int t = threadIdx.x;
    for (int i = t; i < 3 * C1; i += 256) sW1[i] = W1[i];
    sAux[t] = b1[t]; sAux[C1 + t] = As2[t]; sAux[2 * C1 + t] = Ad2[t];
    for (int i = t; i < C1 * OUTC; i += 256) {
        int k = i >> 4, j = i & 15;
        sW2t[j][k] = W2[i];
    }
    __syncthreads();
    int n = t >> 4, l = t & 15;
    int node = blockIdx.x * 16 + n;
    float as = 0.0f, ad = 0.0f;
    for (int i = 0; i < 16; i++) {
        int c = l + 16 * i;
        int h = c >> 5;
        float4 xa = xaccw[node * 8 + h];
        float z = (xa.x * sW1[c] + xa.y * sW1[C1 + c] + xa.z * sW1[2 * C1 + c])
                  / (xa.w + 1e-16f) + sAux[c];
        float e = z > 0.0f ? z : expm1f(z);
        sElu[n][c] = e;
        as = fmaf(e, sAux[C1 + c], as);
        ad = fmaf(e, sAux[2 * C1 + c], ad);
    }
    for (int o = 1; o < 16; o <<= 1) {
        as += __shfl_xor(as, o, 64);
        ad += __shfl_xor(ad, o, 64);
    }
    if (l == 0) { a_s2[node] = as; a_d2[node] = ad; }
    __syncthreads();
    const float4* e4 = (const float4*)&sElu[n][0];
    const float4* w4 = (const float4*)&sW2t[l][0];
    float acc = 0.0f;
    #pragma unroll 8
    for (int k = 0; k < 64; k++) {
        float4 a = e4[k], b = w4[k];
        acc = fmaf(a.x, b.x, fmaf(a.y, b.y, fmaf(a.z, b.z, fmaf(a.w, b.w, acc))));
    }
    h2[node * OUTC + l] = acc;
}

// ---- layer-2 aggregation: 16 lanes per dst (lane = channel) ----
// batch of 16 edges: lane c loads edge base+c's (csr, a_s, exp) in parallel,
// unrolled shfl loop distributes (s,p); h2 gather is 64B coalesced per edge.
__global__ __launch_bounds__(256) void k_agg2(
    const int* __restrict__ off, const int* __restrict__ csr_src,
    const float* __restrict__ a_s, const float* __restrict__ a_d,
    const float* __restrict__ h2, const float* __restrict__ bias,
    float* __restrict__ out)
{
    int tid = threadIdx.x;
    int c = tid & 15;
    int dst = blockIdx.x * 16 + (tid >> 4);
    if (dst >= N_NODES) return;
    int beg = off[dst], end = off[dst + 1];
    float ad = a_d[dst];
    float acc = 0.0f, denp = 0.0f;
    int nfull = beg + ((end - beg) & ~15);
    for (int base = beg; base < nfull; base += 16) {
        int sm = csr_src[base + c];
        float p = __expf(lrelu(a_s[sm] + ad));
        denp += p;
        #pragma unroll
        for (int j = 0; j < 16; j++) {
            int s = __shfl(sm, j, 16);
            float pj = __shfl(p, j, 16);
            acc = fmaf(pj, h2[s * OUTC + c], acc);
        }
    }
    if (nfull < end) {                      // tail (< 16 edges)
        int idx = nfull + c;
        int sm = 0; float p = 0.0f;
        if (idx < end) { sm = csr_src[idx]; p = __expf(lrelu(a_s[sm] + ad)); }
        denp += p;
        int m = end - nfull;
        for (int j = 0; j < m; j++) {
            int s = __shfl(sm, j, 16);
            float pj = __shfl(p, j, 16);
            acc = fmaf(pj, h2[s * OUTC + c], acc);
        }
    }
    for (int o = 1; o < 16; o <<= 1) denp += __shfl_xor(denp, o, 16);
    out[dst * OUTC + c] = acc / (denp + 1e-16f) + bias[c];
}

extern "C" void kernel_launch(void* const* d_in, const int* in_sizes, int n_in,
                              void* d_out, int out_size, void* d_ws, size_t ws_size,
                              hipStream_t stream)
{
    (void)in_sizes; (void)n_in; (void)out_size; (void)ws_size;
    const float* x    = (const float*)d_in[0];
    const int*   ei   = (const int*)d_in[1];
    const float* W1   = (const float*)d_in[2];
    const float* as1w = (const float*)d_in[3];
    const float* ad1w = (const float*)d_in[4];
    const float* b1   = (const float*)d_in[5];
    const float* W2   = (const float*)d_in[6];
    const float* as2w = (const float*)d_in[7];
    const float* ad2w = (const float*)d_in[8];
    const float* b2   = (const float*)d_in[9];
    float* out = (float*)d_out;

    const long N = N_NODES;
    char* p = (char*)d_ws;
    auto alloc = [&](size_t elems) {          // 16B-aligned allocations
        void* r = p; p += ((elems + 3) & ~(size_t)3) * 4; return r;
    };

    float4* xp      = (float4*)alloc(N * 4);
    float4* xaccw   = (float4*)alloc(N * HEADS * 4);
    int*   cnt      = (int*)alloc(N);
    int*   part     = (int*)alloc(N);
    int*   off      = (int*)alloc(N + 1);
    int*   bsum     = (int*)alloc(256);
    int*   rank     = (int*)alloc(E_TOT);
    int*   csr_src  = (int*)alloc(E_TOT);
    float* As1      = (float*)alloc(32);
    float* Ad1      = (float*)alloc(32);
    float* As2      = (float*)alloc(C1);
    float* Ad2      = (float*)alloc(C1);
    float* h2v      = (float*)alloc(N * OUTC);
    float* a_s2     = (float*)alloc(N);
    float* a_d2     = (float*)alloc(N);

    hipMemsetAsync(cnt, 0, (size_t)N * sizeof(int), stream);

    k_setup<<<(E_TOT + 255) / 256, 256, 0, stream>>>(
        x, ei, W1, as1w, ad1w, W2, as2w, ad2w,
        xp, cnt, rank, As1, Ad1, As2, Ad2);
    k_scan1<<<NB1, 256, 0, stream>>>(cnt, part, bsum);
    k_scan2<<<1, 256, 0, stream>>>(bsum);
    k_scan3<<<NB1, 256, 0, stream>>>(part, bsum, off);
    k_fill<<<(E_TOT + 255) / 256, 256, 0, stream>>>(ei, rank, off, csr_src);

    k_agg1<<<(int)((N + 31) / 32), 256, 0, stream>>>(off, csr_src, xp, As1, Ad1, xaccw);
    k_fin1h2<<<(int)(N / 16), 256, 0, stream>>>(xaccw, W1, b1, W2, As2, Ad2, h2v, a_s2, a_d2);
    k_agg2<<<(int)((N + 15) / 16), 256, 0, stream>>>(off, csr_src, a_s2, a_d2, h2v, b2, out);
}